// Round 1
// baseline (284.672 us; speedup 1.0000x reference)
//
#include <hip/hip_runtime.h>

// RoIAlign: features (B=8, C=512, H=60, W=80) fp32, rois (N=1024, 7) fp32
// out (N, C, 7, 7) fp32.
// One block per ROI; 49 bin params precomputed in LDS; main loop strides the
// flattened (c,i,j) = 25088 outputs per ROI across 256 threads so stores are
// fully coalesced. Gathers are served by L1/L2/L3 (features = 78.6 MB < L3).

constexpr int   Cc = 512;
constexpr int   Hh = 60;
constexpr int   Ww = 80;
constexpr int   AH = 7;
constexpr int   AW = 7;
constexpr int   NB = AH * AW;            // 49 bins
constexpr int   OUT_PER_ROI = Cc * NB;   // 25088
constexpr float SCALE = 0.125f;

__global__ __launch_bounds__(256) void roialign_kernel(
    const float* __restrict__ feats,
    const float* __restrict__ rois,
    float* __restrict__ out)
{
    __shared__ int   s_off[NB];   // hi*W + wi (spatial offset of top-left tap)
    __shared__ float s_hr[NB];
    __shared__ float s_wr[NB];
    __shared__ float s_msk[NB];   // validity mask (1.0 / 0.0)
    __shared__ int   s_fbase;     // b * C*H*W

    const int n   = blockIdx.x;
    const int tid = threadIdx.x;
    const float* rp = rois + n * 7;

    if (tid < NB) {
        const float x1 = rp[2] * SCALE, y1 = rp[3] * SCALE;
        const float x2 = rp[4] * SCALE, y2 = rp[5] * SCALE;
        const float bin_h = fmaxf(y2 - y1, 0.0f) * (1.0f / (AH - 1));
        const float bin_w = fmaxf(x2 - x1, 0.0f) * (1.0f / (AW - 1));
        const int i = tid / AW;
        const int j = tid - i * AW;
        const float h = y1 + (float)i * bin_h;
        const float w = x1 + (float)j * bin_w;
        // reference: hstart = min(floor(h), H-2); hr = h - hstart (may be >1)
        const float hs = fminf(floorf(h), (float)(Hh - 2));
        const float ws = fminf(floorf(w), (float)(Ww - 2));
        const int hi = (int)fminf(fmaxf(hs, 0.0f), (float)(Hh - 2));
        const int wi = (int)fminf(fmaxf(ws, 0.0f), (float)(Ww - 2));
        const bool valid = (h >= 0.0f) && (h < (float)Hh) &&
                           (w >= 0.0f) && (w < (float)Ww);
        s_off[tid] = hi * Ww + wi;
        s_hr[tid]  = h - hs;
        s_wr[tid]  = w - ws;
        s_msk[tid] = valid ? 1.0f : 0.0f;
        if (tid == 0) s_fbase = (int)rp[0] * (Cc * Hh * Ww);
    }
    __syncthreads();

    const float* fb = feats + s_fbase;
    float* ob = out + (size_t)n * OUT_PER_ROI;

    // 25088 / 256 = 98 iterations; stores coalesced, 4 gather loads each.
    #pragma unroll 2
    for (int k = tid; k < OUT_PER_ROI; k += 256) {
        const int c  = k / NB;           // magic-mul div by 49
        const int rr = k - c * NB;
        const float* p = fb + c * (Hh * Ww) + s_off[rr];
        const float hr = s_hr[rr];
        const float wr = s_wr[rr];
        const float v00 = p[0];
        const float v01 = p[1];
        const float v10 = p[Ww];
        const float v11 = p[Ww + 1];
        const float top = v00 + (v01 - v00) * wr;   // lerp in w
        const float bot = v10 + (v11 - v10) * wr;
        ob[k] = (top + (bot - top) * hr) * s_msk[rr];
    }
}

extern "C" void kernel_launch(void* const* d_in, const int* in_sizes, int n_in,
                              void* d_out, int out_size, void* d_ws, size_t ws_size,
                              hipStream_t stream) {
    const float* feats = (const float*)d_in[0];
    const float* rois  = (const float*)d_in[1];
    float* out = (float*)d_out;
    const int N = in_sizes[1] / 7;       // 1024 ROIs
    roialign_kernel<<<N, 256, 0, stream>>>(feats, rois, out);
}

// Round 2
// 268.409 us; speedup vs baseline: 1.0606x; 1.0606x over previous
//
#include <hip/hip_runtime.h>

// RoIAlign: features (B=8, C=512, H=60, W=80) fp32, rois (N=1024, 7) fp32
// out (N, C, 7, 7) fp32.
// R2: CSPLIT=4 blocks per ROI (4096 blocks -> 8 blocks/CU, full wave slots),
// same-ROI blocks co-located on one XCD (stride-N block mapping, 1024%8==0),
// packed int4 bin params (one ds_read_b128), nontemporal output stores so the
// 100 MB write stream doesn't evict gather lines from L2.

constexpr int   Cc = 512;
constexpr int   Hh = 60;
constexpr int   Ww = 80;
constexpr int   HW = Hh * Ww;
constexpr int   AH = 7;
constexpr int   AW = 7;
constexpr int   NB = AH * AW;            // 49 bins
constexpr int   CSPLIT = 4;              // blocks per ROI
constexpr int   CPB = Cc / CSPLIT;       // 128 channels per block
constexpr int   OUT_PER_BLK = CPB * NB;  // 6272
constexpr float SCALE = 0.125f;

__global__ __launch_bounds__(256) void roialign_kernel(
    const float* __restrict__ feats,
    const float* __restrict__ rois,
    float* __restrict__ out)
{
    __shared__ int4 s_par[NB];   // {hi*W+wi, hr, wr, msk} bit-packed
    __shared__ int  s_fbase;

    // Same-ROI chunks 1024 apart in blockIdx -> same XCD (round-robin % 8).
    const int n   = blockIdx.x & 1023;        // N = 1024
    const int cs  = blockIdx.x >> 10;         // 0..3
    const int tid = threadIdx.x;
    const float* rp = rois + n * 7;

    if (tid < NB) {
        const float x1 = rp[2] * SCALE, y1 = rp[3] * SCALE;
        const float x2 = rp[4] * SCALE, y2 = rp[5] * SCALE;
        const float bin_h = fmaxf(y2 - y1, 0.0f) * (1.0f / (AH - 1));
        const float bin_w = fmaxf(x2 - x1, 0.0f) * (1.0f / (AW - 1));
        const int i = tid / AW;
        const int j = tid - i * AW;
        const float h = y1 + (float)i * bin_h;
        const float w = x1 + (float)j * bin_w;
        // reference: hstart = min(floor(h), H-2); hr = h - hstart (may be >1)
        const float hs = fminf(floorf(h), (float)(Hh - 2));
        const float ws = fminf(floorf(w), (float)(Ww - 2));
        const int hi = (int)fminf(fmaxf(hs, 0.0f), (float)(Hh - 2));
        const int wi = (int)fminf(fmaxf(ws, 0.0f), (float)(Ww - 2));
        const bool valid = (h >= 0.0f) && (h < (float)Hh) &&
                           (w >= 0.0f) && (w < (float)Ww);
        int4 pr;
        pr.x = hi * Ww + wi;
        pr.y = __float_as_int(h - hs);
        pr.z = __float_as_int(w - ws);
        pr.w = __float_as_int(valid ? 1.0f : 0.0f);
        s_par[tid] = pr;
        if (tid == 0) s_fbase = (int)rp[0] * (Cc * HW);
    }
    __syncthreads();

    const float* fb = feats + s_fbase + cs * (CPB * HW);
    float* ob = out + (size_t)n * (Cc * NB) + cs * OUT_PER_BLK;

    // 6272 / 256 = 24.5 iterations; stores coalesced nontemporal dwords.
    #pragma unroll 4
    for (int k = tid; k < OUT_PER_BLK; k += 256) {
        const int c  = k / NB;           // magic-mul div by 49
        const int rr = k - c * NB;
        const int4 pr = s_par[rr];
        const float hr  = __int_as_float(pr.y);
        const float wr  = __int_as_float(pr.z);
        const float msk = __int_as_float(pr.w);
        const float* p = fb + c * HW + pr.x;
        const float v00 = p[0];
        const float v01 = p[1];
        const float v10 = p[Ww];
        const float v11 = p[Ww + 1];
        const float top = v00 + (v01 - v00) * wr;   // lerp in w
        const float bot = v10 + (v11 - v10) * wr;
        __builtin_nontemporal_store((top + (bot - top) * hr) * msk, &ob[k]);
    }
}

extern "C" void kernel_launch(void* const* d_in, const int* in_sizes, int n_in,
                              void* d_out, int out_size, void* d_ws, size_t ws_size,
                              hipStream_t stream) {
    const float* feats = (const float*)d_in[0];
    const float* rois  = (const float*)d_in[1];
    float* out = (float*)d_out;
    const int N = in_sizes[1] / 7;       // 1024 ROIs
    roialign_kernel<<<N * CSPLIT, 256, 0, stream>>>(feats, rois, out);
}

// Round 3
// 216.423 us; speedup vs baseline: 1.3153x; 1.2402x over previous
//
#include <hip/hip_runtime.h>

// RoIAlign: features (B=8, C=512, H=60, W=80) fp32, rois (N=1024,7) fp32
// out (N, C, 7, 7) fp32.
// R3: XCD<->batch affinity. Prepass builds perm[1024] in d_ws so slot j hosts
// a ROI of batch j%8 (blockIdx%8 -> XCD round-robin heuristic). Combined with
// the cs-phase ordering (blocks 0..1023 = channels 0..127 of every ROI, etc.)
// the concurrent per-XCD L2 footprint is 128ch*60*80*4B = 2.4 MB < 4 MB L2,
// eliminating the ~6x L2 refetch seen in R2 (FETCH_SIZE 500 MB vs 79 MB input).

constexpr int   Bb = 8;
constexpr int   Cc = 512;
constexpr int   Hh = 60;
constexpr int   Ww = 80;
constexpr int   HW = Hh * Ww;
constexpr int   Nn = 1024;
constexpr int   AH = 7;
constexpr int   AW = 7;
constexpr int   NB = AH * AW;            // 49 bins
constexpr int   CSPLIT = 4;              // channel phases
constexpr int   CPB = Cc / CSPLIT;       // 128 channels per block
constexpr int   OUT_PER_BLK = CPB * NB;  // 6272
constexpr int   QUOTA = Nn / Bb;         // 128 slots per batch residue class
constexpr float SCALE = 0.125f;

// ---- prepass: one block, builds perm so perm[j] has batch j%8 when possible
__global__ __launch_bounds__(256) void roi_perm_kernel(
    const float* __restrict__ rois, int* __restrict__ perm)
{
    __shared__ int cnt[Bb];
    __shared__ int ovf[Nn];
    __shared__ int novf;
    __shared__ int ntake;
    const int tid = threadIdx.x;
    if (tid < Bb) cnt[tid] = 0;
    if (tid == 0) { novf = 0; ntake = 0; }
    for (int j = tid; j < Nn; j += 256) perm[j] = -1;
    __syncthreads();
    for (int r = tid; r < Nn; r += 256) {
        const int b = (int)rois[r * 7];
        const int pos = atomicAdd(&cnt[b], 1);
        if (pos < QUOTA) perm[b + Bb * pos] = r;
        else             ovf[atomicAdd(&novf, 1)] = r;
    }
    __syncthreads();
    for (int j = tid; j < Nn; j += 256) {
        if (perm[j] < 0) perm[j] = ovf[atomicAdd(&ntake, 1)];
    }
}

__global__ __launch_bounds__(256) void roialign_kernel(
    const float* __restrict__ feats,
    const float* __restrict__ rois,
    const int* __restrict__ perm,
    float* __restrict__ out)
{
    __shared__ int4 s_par[NB];   // {hi*W+wi, hr, wr, msk} bit-packed
    __shared__ int  s_fbase;

    // slot j keeps j%8 == batch (prepass); cs phases keep co-resident blocks
    // on the same 128-channel slice.
    const int slot = blockIdx.x & (Nn - 1);
    const int cs   = blockIdx.x >> 10;        // 0..CSPLIT-1
    const int n    = perm[slot];
    const int tid  = threadIdx.x;
    const float* rp = rois + n * 7;

    if (tid < NB) {
        const float x1 = rp[2] * SCALE, y1 = rp[3] * SCALE;
        const float x2 = rp[4] * SCALE, y2 = rp[5] * SCALE;
        const float bin_h = fmaxf(y2 - y1, 0.0f) * (1.0f / (AH - 1));
        const float bin_w = fmaxf(x2 - x1, 0.0f) * (1.0f / (AW - 1));
        const int i = tid / AW;
        const int j = tid - i * AW;
        const float h = y1 + (float)i * bin_h;
        const float w = x1 + (float)j * bin_w;
        // reference: hstart = min(floor(h), H-2); hr = h - hstart (may be >1)
        const float hs = fminf(floorf(h), (float)(Hh - 2));
        const float ws = fminf(floorf(w), (float)(Ww - 2));
        const int hi = (int)fminf(fmaxf(hs, 0.0f), (float)(Hh - 2));
        const int wi = (int)fminf(fmaxf(ws, 0.0f), (float)(Ww - 2));
        const bool valid = (h >= 0.0f) && (h < (float)Hh) &&
                           (w >= 0.0f) && (w < (float)Ww);
        int4 pr;
        pr.x = hi * Ww + wi;
        pr.y = __float_as_int(h - hs);
        pr.z = __float_as_int(w - ws);
        pr.w = __float_as_int(valid ? 1.0f : 0.0f);
        s_par[tid] = pr;
        if (tid == 0) s_fbase = (int)rp[0] * (Cc * HW);
    }
    __syncthreads();

    const float* fb = feats + s_fbase + cs * (CPB * HW);
    float* ob = out + (size_t)n * (Cc * NB) + cs * OUT_PER_BLK;

    #pragma unroll 4
    for (int k = tid; k < OUT_PER_BLK; k += 256) {
        const int c  = k / NB;           // magic-mul div by 49
        const int rr = k - c * NB;
        const int4 pr = s_par[rr];
        const float hr  = __int_as_float(pr.y);
        const float wr  = __int_as_float(pr.z);
        const float msk = __int_as_float(pr.w);
        const float* p = fb + c * HW + pr.x;
        const float v00 = p[0];
        const float v01 = p[1];
        const float v10 = p[Ww];
        const float v11 = p[Ww + 1];
        const float top = v00 + (v01 - v00) * wr;   // lerp in w
        const float bot = v10 + (v11 - v10) * wr;
        __builtin_nontemporal_store((top + (bot - top) * hr) * msk, &ob[k]);
    }
}

extern "C" void kernel_launch(void* const* d_in, const int* in_sizes, int n_in,
                              void* d_out, int out_size, void* d_ws, size_t ws_size,
                              hipStream_t stream) {
    const float* feats = (const float*)d_in[0];
    const float* rois  = (const float*)d_in[1];
    float* out = (float*)d_out;
    int* perm = (int*)d_ws;              // 1024 ints
    roi_perm_kernel<<<1, 256, 0, stream>>>(rois, perm);
    roialign_kernel<<<Nn * CSPLIT, 256, 0, stream>>>(feats, rois, perm, out);
}